// Round 2
// baseline (257.112 us; speedup 1.0000x reference)
//
#include <hip/hip_runtime.h>
#include <hip/hip_bf16.h>

#define N_POINTS 262144
#define SP_FEAT 128
#define HIDDEN 64
#define EMBED 256
#define NUM_SP 4096
#define NUM_SP2 256
#define PAD_LIMIT 64

typedef __bf16 bf16x8 __attribute__((ext_vector_type(8)));
typedef float floatx4 __attribute__((ext_vector_type(4)));
using bf16 = __hip_bfloat16;

// ---------------------------------------------------------------------------
// Prep: transpose + fp32->bf16 weights so MFMA B-fragments are contiguous in k.
// W1 fp32 [128][64] -> W1t bf16 [64][128];  W2 fp32 [64][256] -> W2t bf16 [256][64]
// ---------------------------------------------------------------------------
__global__ void prep_kernel(const float* __restrict__ W1, const float* __restrict__ W2,
                            bf16* __restrict__ W1t, bf16* __restrict__ W2t) {
    int i = blockIdx.x * blockDim.x + threadIdx.x;
    if (i < HIDDEN * SP_FEAT) {
        int n = i >> 7;        // / 128
        int k = i & 127;
        W1t[i] = __float2bfloat16(W1[k * HIDDEN + n]);
    }
    int j = i - HIDDEN * SP_FEAT;
    if (j >= 0 && j < EMBED * HIDDEN) {
        int n = j >> 6;        // / 64
        int k = j & 63;
        W2t[j] = __float2bfloat16(W2[k * EMBED + n]);
    }
}

// ---------------------------------------------------------------------------
// Fused MLP (x@W1 relu @W2 relu) + sorted-segment max via atomicMax.
// One block = 64 consecutive points. 256 threads = 4 waves.
// GEMM1: [64,128]@[128,64] -> H1 (LDS, bf16). GEMM2: [64,64]@[64,256].
// tok_bits: fp32 bits (all values >= 0 after relu, so int-ordered), init 0.
// ---------------------------------------------------------------------------
__global__ __launch_bounds__(256) void mlp_segmax_kernel(
    const float* __restrict__ X, const int* __restrict__ idx10,
    const bf16* __restrict__ W1t, const float* __restrict__ b1,
    const bf16* __restrict__ W2t, const float* __restrict__ b2,
    int* __restrict__ tok_bits)
{
    // padded stride 136 elems = 272 B (16B-aligned rows, bank-shifted)
    __shared__ __align__(16) bf16 Xs[64][136];
    __shared__ __align__(16) bf16 H1s[64][72];   // 144 B stride
    __shared__ int sIdx[64];

    const int tid  = threadIdx.x;
    const int lane = tid & 63;
    const int w    = tid >> 6;       // wave 0..3
    const int l15  = lane & 15;
    const int quad = lane >> 4;
    const int m0   = blockIdx.x * 64;

    // --- B-fragments for both GEMMs straight from global (cache-hot, 48 KB)
    bf16x8 bw1[4];                   // GEMM1: W1t row n = 16w+l15, k = 32ks+quad*8
    {
        const bf16* p = W1t + (16 * w + l15) * SP_FEAT + quad * 8;
#pragma unroll
        for (int ks = 0; ks < 4; ++ks)
            bw1[ks] = *(const bf16x8*)(p + 32 * ks);
    }
    bf16x8 bf2[4][2];                // GEMM2: W2t row n = 64w+16tn+l15
#pragma unroll
    for (int tn = 0; tn < 4; ++tn) {
        const bf16* p = W2t + (64 * w + 16 * tn + l15) * HIDDEN + quad * 8;
#pragma unroll
        for (int ks = 0; ks < 2; ++ks)
            bf2[tn][ks] = *(const bf16x8*)(p + 32 * ks);
    }
    float b2f[4];
#pragma unroll
    for (int tn = 0; tn < 4; ++tn)
        b2f[tn] = b2[64 * w + 16 * tn + l15];
    const float b1v = b1[16 * w + l15];

    // --- stage X tile [64][128] fp32 -> bf16 LDS (each thread: 8 elems x 4 iters)
#pragma unroll
    for (int i = 0; i < 4; ++i) {
        int c   = tid + 256 * i;         // 0..1023
        int row = c >> 4;
        int cc  = (c & 15) * 8;
        const float* src = X + (size_t)(m0 + row) * SP_FEAT + cc;
        float4 u0 = *(const float4*)src;
        float4 u1 = *(const float4*)(src + 4);
        union { bf16x8 v; bf16 h[8]; } u;
        u.h[0] = __float2bfloat16(u0.x); u.h[1] = __float2bfloat16(u0.y);
        u.h[2] = __float2bfloat16(u0.z); u.h[3] = __float2bfloat16(u0.w);
        u.h[4] = __float2bfloat16(u1.x); u.h[5] = __float2bfloat16(u1.y);
        u.h[6] = __float2bfloat16(u1.z); u.h[7] = __float2bfloat16(u1.w);
        *(bf16x8*)(&Xs[row][cc]) = u.v;
    }
    if (tid < 64) sIdx[tid] = idx10[m0 + tid];
    __syncthreads();

    // --- GEMM1: wave w computes H1 cols [16w,16w+16), all 64 rows, K=128
    floatx4 zero4 = {0.f, 0.f, 0.f, 0.f};
    floatx4 acc1[4] = {zero4, zero4, zero4, zero4};
#pragma unroll
    for (int ks = 0; ks < 4; ++ks) {
        int k = ks * 32 + quad * 8;
#pragma unroll
        for (int tm = 0; tm < 4; ++tm) {
            bf16x8 a = *(bf16x8*)(&Xs[16 * tm + l15][k]);
            acc1[tm] = __builtin_amdgcn_mfma_f32_16x16x32_bf16(a, bw1[ks], acc1[tm], 0, 0, 0);
        }
    }
    // D-layout (row = quad*4+r, col = l15) -> H1 LDS (A-layout for GEMM2)
#pragma unroll
    for (int tm = 0; tm < 4; ++tm) {
#pragma unroll
        for (int r = 0; r < 4; ++r) {
            float v = acc1[tm][r] + b1v;
            v = v > 0.f ? v : 0.f;
            H1s[16 * tm + quad * 4 + r][16 * w + l15] = __float2bfloat16(v);
        }
    }
    __syncthreads();

    // --- GEMM2: wave w computes cols [64w,64w+64), all rows, K=64
    floatx4 acc2[4][4];
#pragma unroll
    for (int tm = 0; tm < 4; ++tm)
#pragma unroll
        for (int tn = 0; tn < 4; ++tn) acc2[tm][tn] = zero4;
#pragma unroll
    for (int tm = 0; tm < 4; ++tm) {
        bf16x8 a0 = *(bf16x8*)(&H1s[16 * tm + l15][quad * 8]);
        bf16x8 a1 = *(bf16x8*)(&H1s[16 * tm + l15][32 + quad * 8]);
#pragma unroll
        for (int tn = 0; tn < 4; ++tn) {
            acc2[tm][tn] = __builtin_amdgcn_mfma_f32_16x16x32_bf16(a0, bf2[tn][0], acc2[tm][tn], 0, 0, 0);
            acc2[tm][tn] = __builtin_amdgcn_mfma_f32_16x16x32_bf16(a1, bf2[tn][1], acc2[tm][tn], 0, 0, 0);
        }
    }

    // --- epilogue: relu + bias, run-merged segment max across ALL 16 rows a
    //     lane owns (rows 16*tm + quad*4 + r are strictly increasing in (tm,r),
    //     idx10 sorted => equal ids are contiguous in this subsequence)
#pragma unroll
    for (int tn = 0; tn < 4; ++tn) {
        int col = 64 * w + 16 * tn + l15;
        float cur = 0.f;
        int cursp = -1;
#pragma unroll
        for (int tm = 0; tm < 4; ++tm) {
            int r0 = 16 * tm + quad * 4;
#pragma unroll
            for (int r = 0; r < 4; ++r) {
                float v = acc2[tm][tn][r] + b2f[tn];
                v = v > 0.f ? v : 0.f;
                int sp = sIdx[r0 + r];
                if (sp == cursp) {
                    cur = fmaxf(cur, v);
                } else {
                    if (cursp >= 0)
                        atomicMax(&tok_bits[cursp * EMBED + col], __float_as_int(cur));
                    cursp = sp;
                    cur = v;
                }
            }
        }
        atomicMax(&tok_bits[cursp * EMBED + col], __float_as_int(cur));
    }
}

// ---------------------------------------------------------------------------
// Rank (within sp2 group, separate for remain/mask) + scatter to padded out.
// idx21 sorted; one block per sp2 group; rank j -> slot j (< PAD_LIMIT kept).
// is_masked encoding (1-byte bool vs int32) detected at runtime.
// ---------------------------------------------------------------------------
__global__ __launch_bounds__(256) void scatter_kernel(
    const float* __restrict__ tok, const int* __restrict__ idx21,
    const void* __restrict__ is_masked, float* __restrict__ out)
{
    __shared__ int lspR[PAD_LIMIT], lspM[PAD_LIMIT];
    __shared__ int cnt[2];
    __shared__ int enc;   // 1 = byte-bool encoding, 0 = int32 encoding
    const int g = blockIdx.x;
    const int tid = threadIdx.x;

    if (tid == 0) enc = 0;
    __syncthreads();
    {
        const unsigned char* mb = (const unsigned char*)is_masked;
        int local = 0;
        for (int p = tid; p < NUM_SP; p += 256)
            if ((p & 3) && mb[p]) local = 1;
        if (local) atomicOr(&enc, 1);
    }
    __syncthreads();
    const int e = enc;

    if (tid == 0) {
        const unsigned char* mb = (const unsigned char*)is_masked;
        const int* mi = (const int*)is_masked;
        int a = 0, b = NUM_SP;
        while (a < b) { int m = (a + b) >> 1; if (idx21[m] < g) a = m + 1; else b = m; }
        int lo = a;
        b = NUM_SP;
        while (a < b) { int m = (a + b) >> 1; if (idx21[m] < g + 1) a = m + 1; else b = m; }
        int hi = a;
        int nR = 0, nM = 0;
        for (int s = lo; s < hi; ++s) {
            int msk = e ? (int)mb[s] : mi[s];
            if (msk) { if (nM < PAD_LIMIT) lspM[nM] = s; nM++; }
            else     { if (nR < PAD_LIMIT) lspR[nR] = s; nR++; }
        }
        cnt[0] = nR < PAD_LIMIT ? nR : PAD_LIMIT;
        cnt[1] = nM < PAD_LIMIT ? nM : PAD_LIMIT;
    }
    __syncthreads();
    const int nR = cnt[0], nM = cnt[1];
    float* outR = out + (size_t)g * PAD_LIMIT * EMBED;
    float* outM = out + (size_t)NUM_SP2 * PAD_LIMIT * EMBED + (size_t)g * PAD_LIMIT * EMBED;
    for (int r = 0; r < nR; ++r)
        outR[r * EMBED + tid] = tok[lspR[r] * EMBED + tid];
    for (int r = 0; r < nM; ++r)
        outM[r * EMBED + tid] = tok[lspM[r] * EMBED + tid];
}

// ---------------------------------------------------------------------------
extern "C" void kernel_launch(void* const* d_in, const int* in_sizes, int n_in,
                              void* d_out, int out_size, void* d_ws, size_t ws_size,
                              hipStream_t stream) {
    (void)in_sizes; (void)n_in; (void)ws_size;
    const float* X       = (const float*)d_in[0];
    const int* idx10     = (const int*)d_in[1];
    const int* idx21     = (const int*)d_in[2];
    const void* is_masked= (const void*)d_in[3];
    const float* W1      = (const float*)d_in[4];
    const float* b1      = (const float*)d_in[5];
    const float* W2      = (const float*)d_in[6];
    const float* b2      = (const float*)d_in[7];
    float* out           = (float*)d_out;

    char* ws   = (char*)d_ws;
    float* tok = (float*)ws;                                   // 4 MB fp32
    bf16* W1t  = (bf16*)(ws + (size_t)NUM_SP * EMBED * 4);     // 16 KB
    bf16* W2t  = W1t + HIDDEN * SP_FEAT;                       // 32 KB

    hipMemsetAsync(tok, 0, (size_t)NUM_SP * EMBED * sizeof(float), stream);
    hipMemsetAsync(d_out, 0, (size_t)out_size * sizeof(float), stream);

    prep_kernel<<<(HIDDEN * SP_FEAT + EMBED * HIDDEN + 255) / 256, 256, 0, stream>>>(
        W1, W2, W1t, W2t);
    mlp_segmax_kernel<<<N_POINTS / 64, 256, 0, stream>>>(
        X, idx10, W1t, b1, W2t, b2, (int*)tok);
    scatter_kernel<<<NUM_SP2, 256, 0, stream>>>(tok, idx21, is_masked, out);
}